// Round 10
// baseline (263.802 us; speedup 1.0000x reference)
//
#include <hip/hip_runtime.h>

#define S 4096
#define BATCH 2
#define D 768
#define NH 12
#define DH 64
#define NROWS (BATCH * S)
#define N_ITEMS (32 * NH * BATCH)          // 768 (qt, h, b) work items
#define CTR_OFF 67633152                   // byte offset of queue counter in ws

typedef __attribute__((ext_vector_type(8))) short bf16x8;   // 8 bf16 (4 VGPRs)
typedef __attribute__((ext_vector_type(4))) float f32x4;

__device__ __forceinline__ unsigned short f2bf(float f) {
    unsigned u = __builtin_bit_cast(unsigned, f);
    u += 0x7fff + ((u >> 16) & 1);          // round-to-nearest-even
    return (unsigned short)(u >> 16);
}

__device__ __forceinline__ float fexp2(float x) {
#if __has_builtin(__builtin_amdgcn_exp2f)
    return __builtin_amdgcn_exp2f(x);       // raw v_exp_f32
#else
    return exp2f(x);
#endif
}

// async global->LDS, 16B per lane; lds ptr must be wave-uniform
#define GLDS16(g, l)                                                   \
    __builtin_amdgcn_global_load_lds(                                  \
        (const __attribute__((address_space(1))) void*)(g),            \
        (__attribute__((address_space(3))) void*)(l), 16, 0, 0)

// ---------------------------------------------------------------------------
// x (fp32 [8192][768]) -> bf16. grid 6144 x 256.
// ---------------------------------------------------------------------------
__global__ __launch_bounds__(256) void cvt_x(const float* __restrict__ x,
                                             unsigned short* __restrict__ xb)
{
    int i = (blockIdx.x * 256 + threadIdx.x) * 4;
    float4 v = *(const float4*)(x + i);
    ushort4 o = make_ushort4(f2bf(v.x), f2bf(v.y), f2bf(v.z), f2bf(v.w));
    *(ushort4*)(xb + i) = o;
}

// ---------------------------------------------------------------------------
// W[k][n] fp32 -> wt[z][n][k] bf16 (transposed), z in {Wq,Wk,Wv,Wo}.
// grid (24, 24, 4) x 256; 32x32 LDS tile.
// ---------------------------------------------------------------------------
__global__ __launch_bounds__(256) void cvt_w(
    const float* __restrict__ Wq, const float* __restrict__ Wk,
    const float* __restrict__ Wv, const float* __restrict__ Wo,
    unsigned short* __restrict__ wt)
{
    __shared__ float tile[32][33];
    const int z = blockIdx.z;
    const float* W = (z == 0) ? Wq : (z == 1) ? Wk : (z == 2) ? Wv : Wo;
    const int k0 = blockIdx.x * 32, n0 = blockIdx.y * 32;
    const int t = threadIdx.x;
    const int r = t >> 3, c4 = (t & 7) * 4;

    float4 v = *(const float4*)(W + (size_t)(k0 + r) * D + n0 + c4);
    tile[r][c4 + 0] = v.x; tile[r][c4 + 1] = v.y;
    tile[r][c4 + 2] = v.z; tile[r][c4 + 3] = v.w;
    __syncthreads();
    ushort4 o = make_ushort4(f2bf(tile[c4 + 0][r]), f2bf(tile[c4 + 1][r]),
                             f2bf(tile[c4 + 2][r]), f2bf(tile[c4 + 3][r]));
    *(ushort4*)(wt + ((size_t)z * D + n0 + r) * D + k0 + c4) = o;
}

// ---------------------------------------------------------------------------
// QKV GEMM, bf16 MFMA. A = xb [8192][768], B = wt[z][n][k] (z = n0/768).
// 128x128 tile, BK=64, global_load_lds staging with XOR-8 swizzle.
// Q is pre-scaled by 0.125*log2(e) so attention softmax can use exp2.
// V epilogue: LDS-bounce transpose -> coalesced 16B stores along s.
// grid (64, 18).
// ---------------------------------------------------------------------------
__global__ __launch_bounds__(256) void gemm_qkv(
    const unsigned short* __restrict__ xb,
    const unsigned short* __restrict__ wt,
    unsigned short* __restrict__ qb, unsigned short* __restrict__ kb,
    unsigned short* __restrict__ vtb)
{
    __shared__ unsigned short SMEM[2 * 128 * 64];   // As | Bs, reused as bounce
    unsigned short* As = SMEM;
    unsigned short* Bs = SMEM + 128 * 64;

    const int t = threadIdx.x;
    const int lane = t & 63, w = t >> 6;
    const int l16 = lane & 15, quad = lane >> 4;
    const int wm = w & 1, wn = w >> 1;
    const int m0 = blockIdx.x * 128;
    const int n0g = blockIdx.y * 128;
    const int z = n0g / 768;
    const int c0 = n0g - z * 768;
    const unsigned short* Wz = wt + (size_t)z * D * D;

    f32x4 acc[4][4] = {};

    for (int k0 = 0; k0 < D; k0 += 64) {
#pragma unroll
        for (int i = 0; i < 4; ++i) {
            int g = i * 256 + w * 64 + lane;
            int row = g >> 3, cl = g & 7, cg = cl ^ (row & 7);
            GLDS16(xb + (size_t)(m0 + row) * D + k0 + cg * 8,
                   As + (size_t)(i * 256 + w * 64) * 8);
            GLDS16(Wz + (size_t)(c0 + row) * D + k0 + cg * 8,
                   Bs + (size_t)(i * 256 + w * 64) * 8);
        }
        __syncthreads();
#pragma unroll
        for (int kk = 0; kk < 2; ++kk) {
            bf16x8 af[4], bf_[4];
#pragma unroll
            for (int mt = 0; mt < 4; ++mt) {
                int r = wm * 64 + mt * 16 + l16;
                int c = kk * 4 + quad;
                af[mt] = *(const bf16x8*)&As[(r * 8 + (c ^ (r & 7))) * 8];
            }
#pragma unroll
            for (int nt = 0; nt < 4; ++nt) {
                int r = wn * 64 + nt * 16 + l16;
                int c = kk * 4 + quad;
                bf_[nt] = *(const bf16x8*)&Bs[(r * 8 + (c ^ (r & 7))) * 8];
            }
#pragma unroll
            for (int mt = 0; mt < 4; ++mt)
#pragma unroll
                for (int nt = 0; nt < 4; ++nt)
                    acc[mt][nt] = __builtin_amdgcn_mfma_f32_16x16x32_bf16(
                        af[mt], bf_[nt], acc[mt][nt], 0, 0, 0);
        }
        __syncthreads();
    }

    if (z < 2) {
        unsigned short* outp = (z == 0) ? qb : kb;
        const float scale = (z == 0) ? 0.18033688011112042f : 1.0f; // .125*log2e
#pragma unroll
        for (int mt = 0; mt < 4; ++mt) {
#pragma unroll
            for (int reg = 0; reg < 4; ++reg) {
                int m = wm * 64 + mt * 16 + quad * 4 + reg;
                int ng = m0 + m;
                int b = ng >> 12, s = ng & 4095;
#pragma unroll
                for (int nt = 0; nt < 4; ++nt) {
                    int n = c0 + wn * 64 + nt * 16 + l16;
                    int h = n >> 6, dh = n & 63;
                    outp[(((size_t)b * NH + h) * S + s) * DH + dh] =
                        f2bf(acc[mt][nt][reg] * scale);
                }
            }
        }
    } else {
        // V^T via LDS bounce: two dh-halves of the 128x128 tile.
        // fb layout: [dh_local 0..63][s_local 0..127 (+8 pad)], bf16.
        unsigned short* fb = SMEM;
        const int bloc = m0 >> 12;           // batch index
        const int srel = m0 & 4095;          // s offset within batch
        for (int hh2 = 0; hh2 < 2; ++hh2) {
            __syncthreads();
            if (wn == hh2) {
#pragma unroll
                for (int nt = 0; nt < 4; ++nt) {
                    int dh_l = nt * 16 + l16;
#pragma unroll
                    for (int mt = 0; mt < 4; ++mt) {
                        int s_l = wm * 64 + mt * 16 + quad * 4;
                        ushort4 p = make_ushort4(
                            f2bf(acc[mt][nt][0]), f2bf(acc[mt][nt][1]),
                            f2bf(acc[mt][nt][2]), f2bf(acc[mt][nt][3]));
                        *(ushort4*)&fb[dh_l * 136 + s_l] = p;
                    }
                }
            }
            __syncthreads();
            int dh_l = t >> 2;               // 0..63
            int s0 = (t & 3) * 32;           // 4 chunks of 8
            int n = c0 + hh2 * 64 + dh_l;
            int head = n >> 6, dh = n & 63;
            size_t vbase = (((size_t)bloc * NH + head) * DH + dh) * S + srel;
#pragma unroll
            for (int i = 0; i < 4; ++i) {
                int s_l = s0 + i * 8;
                *(uint4*)(vtb + vbase + s_l) = *(const uint4*)&fb[dh_l * 136 + s_l];
            }
        }
    }
}

// ---------------------------------------------------------------------------
// Flash attention v6b: dynamic work queue + fixed-max softmax (see r8) +
// LDS-bounced coalesced ctxb stores. Scratch stride 72 (144B rows) so the
// uint4 readback is 16B-aligned for every row.
// Block 256 = 4 waves x 32 q-rows. LDS: K/V dbuf 32K + Ps 16K = 48K.
// ---------------------------------------------------------------------------
__global__ __launch_bounds__(256) void attn_mfma(
    const unsigned short* __restrict__ qg,
    const unsigned short* __restrict__ kg,
    const unsigned short* __restrict__ vtg,
    unsigned short* __restrict__ ctxb,
    int* __restrict__ work_ctr)
{
    __shared__ unsigned short Ks[2][64 * 64];  // [key][dh], XOR-8 swizzle
    __shared__ unsigned short Vs[2][64 * 64];  // [dh][key], XOR-8 swizzle
    __shared__ unsigned short Ps[4][32][64];   // per-wave P: [qrow32][key]
    __shared__ int s_item;

    const float INF = __builtin_inff();
    const int t = threadIdx.x;
    const int w = t >> 6, lane = t & 63;
    const int l16 = lane & 15, quad = lane >> 4;
    const int a7 = l16 & 7;
    const int sg = w * 64 + lane;

    for (;;) {
        if (t == 0) s_item = atomicAdd(work_ctr, 1);
        __syncthreads();                 // broadcast item; prior LDS use done
        const int p = s_item;
        if (p >= N_ITEMS) return;        // uniform exit

        const int qt = 31 - (p / (NH * BATCH));   // longest first
        const int hb = p % (NH * BATCH);
        const int h = hb % NH, b = hb / NH;
        const size_t hbase = ((size_t)b * NH + h) * (size_t)S * DH;
        const unsigned short* kp = kg + hbase;
        const unsigned short* vp = vtg + hbase;

        // Q^T B-fragments for 2 strips (reused across all tiles)
        bf16x8 bq[2][2];
#pragma unroll
        for (int qs = 0; qs < 2; ++qs) {
            int qrow = qt * 128 + w * 32 + qs * 16 + l16;
#pragma unroll
            for (int kk = 0; kk < 2; ++kk)
                bq[qs][kk] = *(const bf16x8*)(qg + hbase + (size_t)qrow * DH +
                                              kk * 32 + quad * 8);
        }

        f32x4 acc_o[2][4] = {};          // O^T: row = dh-local, col = qrow = l16
        float lsum[2] = {0.f, 0.f};      // lane-local partial row sums

        const int jmax = 2 * qt + 1, jd = 2 * qt;

        // preload tile 0 into buffer 0
#pragma unroll
        for (int i = 0; i < 2; ++i) {
            int g = i * 256 + sg;
            int row = g >> 3, cl = g & 7, cg = cl ^ (row & 7);
            GLDS16(kp + (size_t)row * DH + cg * 8,
                   &Ks[0][(size_t)(i * 256 + w * 64) * 8]);
            GLDS16(vp + (size_t)row * S + cg * 8,
                   &Vs[0][(size_t)(i * 256 + w * 64) * 8]);
        }

        for (int j = 0; j <= jmax; ++j) {
            const int cur = j & 1;
            __syncthreads();             // drains tile-j loads; buf cur^1 free
            if (j < jmax) {              // prefetch j+1, overlaps compute
#pragma unroll
                for (int i = 0; i < 2; ++i) {
                    int g = i * 256 + sg;
                    int row = g >> 3, cl = g & 7, cg = cl ^ (row & 7);
                    GLDS16(kp + (size_t)((j + 1) * 64 + row) * DH + cg * 8,
                           &Ks[cur ^ 1][(size_t)(i * 256 + w * 64) * 8]);
                    GLDS16(vp + (size_t)row * S + (j + 1) * 64 + cg * 8,
                           &Vs[cur ^ 1][(size_t)(i * 256 + w * 64) * 8]);
                }
            }

            const unsigned short* Kc = Ks[cur];
            const unsigned short* Vc = Vs[cur];

            // --- S^T = K Q^T ---
            f32x4 acc_s[2][4] = {};
#pragma unroll
            for (int kk = 0; kk < 2; ++kk)
#pragma unroll
                for (int ms = 0; ms < 4; ++ms) {
                    int r = ms * 16 + l16, c = kk * 4 + quad;
                    bf16x8 ak = *(const bf16x8*)&Kc[(r * 8 + (c ^ a7)) * 8];
#pragma unroll
                    for (int qs = 0; qs < 2; ++qs)
                        acc_s[qs][ms] = __builtin_amdgcn_mfma_f32_16x16x32_bf16(
                            ak, bq[qs][kk], acc_s[qs][ms], 0, 0, 0);
                }

            // --- causal mask: only the 2 diagonal tiles (uniform branch) ---
            if (j >= jd) {
#pragma unroll
                for (int qs = 0; qs < 2; ++qs) {
                    int qrow_g = qt * 128 + w * 32 + qs * 16 + l16;
#pragma unroll
                    for (int ms = 0; ms < 4; ++ms)
#pragma unroll
                        for (int reg = 0; reg < 4; ++reg)
                            if ((j * 64 + ms * 16 + quad * 4 + reg) > qrow_g)
                                acc_s[qs][ms][reg] = -INF;   // exp2 -> 0
                }
            }

            // --- fixed-max softmax: P = exp2(S), lane-local partial sums ---
#pragma unroll
            for (int qs = 0; qs < 2; ++qs) {
#pragma unroll
                for (int ms = 0; ms < 4; ++ms) {
                    float e0 = fexp2(acc_s[qs][ms][0]);
                    float e1 = fexp2(acc_s[qs][ms][1]);
                    float e2 = fexp2(acc_s[qs][ms][2]);
                    float e3 = fexp2(acc_s[qs][ms][3]);
                    lsum[qs] += (e0 + e1) + (e2 + e3);
                    unsigned u01 = __builtin_amdgcn_perm(
                        __builtin_bit_cast(unsigned, e1),
                        __builtin_bit_cast(unsigned, e0), 0x07060302u);
                    unsigned u23 = __builtin_amdgcn_perm(
                        __builtin_bit_cast(unsigned, e3),
                        __builtin_bit_cast(unsigned, e2), 0x07060302u);
                    int c8 = ms * 2 + (quad >> 1);
                    *(uint2*)&Ps[w][qs * 16 + l16]
                               [(c8 ^ a7) * 8 + (quad & 1) * 4] =
                        make_uint2(u01, u23);
                }
            }

            // --- O^T += V^T P^T (no rescale needed) ---
#pragma unroll
            for (int kk = 0; kk < 2; ++kk) {
                bf16x8 bp[2];
#pragma unroll
                for (int qs = 0; qs < 2; ++qs)
                    bp[qs] = *(const bf16x8*)&Ps[w][qs * 16 + l16]
                                                [((kk * 4 + quad) ^ a7) * 8];
#pragma unroll
                for (int d = 0; d < 4; ++d) {
                    int r = d * 16 + l16, c = kk * 4 + quad;
                    bf16x8 av = *(const bf16x8*)&Vc[(r * 8 + (c ^ a7)) * 8];
#pragma unroll
                    for (int qs = 0; qs < 2; ++qs)
                        acc_o[qs][d] = __builtin_amdgcn_mfma_f32_16x16x32_bf16(
                            av, bp[qs], acc_o[qs][d], 0, 0, 0);
                }
            }
        }

        // --- epilogue: reduce lsum, bounce O^T through LDS (Ks/Vs free as
        //     scratch; stride 72 shorts = 144B rows -> 16B-aligned reads),
        //     then coalesced 16B ctxb stores ---
        __syncthreads();                 // all waves done reading Ks/Vs
        unsigned short* pb = (w < 2) ? (&Ks[0][0] + w * 2304)
                                     : (&Vs[0][0] + (w - 2) * 2304);
#pragma unroll
        for (int qs = 0; qs < 2; ++qs) {
            float tot = lsum[qs];
            tot += __shfl_xor(tot, 16);
            tot += __shfl_xor(tot, 32);
            float inv = 1.f / tot;
#pragma unroll
            for (int d = 0; d < 4; ++d) {
                ushort4 o;
                o.x = f2bf(acc_o[qs][d][0] * inv);
                o.y = f2bf(acc_o[qs][d][1] * inv);
                o.z = f2bf(acc_o[qs][d][2] * inv);
                o.w = f2bf(acc_o[qs][d][3] * inv);
                *(ushort4*)&pb[(qs * 16 + l16) * 72 + d * 16 + quad * 4] = o;
            }
        }
        // same wave wrote its pb region; in-order LDS pipe + compiler
        // lgkmcnt makes the readback safe without a barrier.
        {
            int qrow_l = lane >> 1;
            int dh0 = (lane & 1) * 32;
            int qrow = qt * 128 + w * 32 + qrow_l;
            size_t base = ((size_t)(b * S + qrow)) * D + h * 64;
#pragma unroll
            for (int i = 0; i < 4; ++i) {
                uint4 v = *(const uint4*)&pb[qrow_l * 72 + dh0 + i * 8];
                *(uint4*)(ctxb + base + dh0 + i * 8) = v;
            }
        }
    }
}

// ---------------------------------------------------------------------------
// Output projection, bf16 MFMA. A = ctxb [8192][768], B = wt[3] (Wo^T),
// +bias, fp32 out. grid (64, 6).
// ---------------------------------------------------------------------------
__global__ __launch_bounds__(256) void gemm_out(
    const unsigned short* __restrict__ ctxb,
    const unsigned short* __restrict__ wt,
    const float* __restrict__ bo,
    float* __restrict__ out)
{
    __shared__ unsigned short As[128 * 64];
    __shared__ unsigned short Bs[128 * 64];

    const int t = threadIdx.x;
    const int lane = t & 63, w = t >> 6;
    const int l16 = lane & 15, quad = lane >> 4;
    const int wm = w & 1, wn = w >> 1;
    const int m0 = blockIdx.x * 128;
    const int n0 = blockIdx.y * 128;
    const unsigned short* Wz = wt + (size_t)3 * D * D;

    f32x4 acc[4][4] = {};

    for (int k0 = 0; k0 < D; k0 += 64) {
#pragma unroll
        for (int i = 0; i < 4; ++i) {
            int g = i * 256 + w * 64 + lane;
            int row = g >> 3, cl = g & 7, cg = cl ^ (row & 7);
            GLDS16(ctxb + (size_t)(m0 + row) * D + k0 + cg * 8,
                   As + (size_t)(i * 256 + w * 64) * 8);
            GLDS16(Wz + (size_t)(n0 + row) * D + k0 + cg * 8,
                   Bs + (size_t)(i * 256 + w * 64) * 8);
        }
        __syncthreads();
#pragma unroll
        for (int kk = 0; kk < 2; ++kk) {
            bf16x8 af[4], bf_[4];
#pragma unroll
            for (int mt = 0; mt < 4; ++mt) {
                int r = wm * 64 + mt * 16 + l16;
                int c = kk * 4 + quad;
                af[mt] = *(const bf16x8*)&As[(r * 8 + (c ^ (r & 7))) * 8];
            }
#pragma unroll
            for (int nt = 0; nt < 4; ++nt) {
                int r = wn * 64 + nt * 16 + l16;
                int c = kk * 4 + quad;
                bf_[nt] = *(const bf16x8*)&Bs[(r * 8 + (c ^ (r & 7))) * 8];
            }
#pragma unroll
            for (int mt = 0; mt < 4; ++mt)
#pragma unroll
                for (int nt = 0; nt < 4; ++nt)
                    acc[mt][nt] = __builtin_amdgcn_mfma_f32_16x16x32_bf16(
                        af[mt], bf_[nt], acc[mt][nt], 0, 0, 0);
        }
        __syncthreads();
    }

    float bv[4];
#pragma unroll
    for (int nt = 0; nt < 4; ++nt)
        bv[nt] = bo[n0 + wn * 64 + nt * 16 + l16];
#pragma unroll
    for (int mt = 0; mt < 4; ++mt)
#pragma unroll
        for (int reg = 0; reg < 4; ++reg) {
            int m = m0 + wm * 64 + mt * 16 + quad * 4 + reg;
#pragma unroll
            for (int nt = 0; nt < 4; ++nt)
                out[(size_t)m * D + n0 + wn * 64 + nt * 16 + l16] =
                    acc[mt][nt][reg] + bv[nt];
        }
}

extern "C" void kernel_launch(void* const* d_in, const int* in_sizes, int n_in,
                              void* d_out, int out_size, void* d_ws, size_t ws_size,
                              hipStream_t stream)
{
    const float* x  = (const float*)d_in[0];
    const float* Wq = (const float*)d_in[1];
    const float* Wk = (const float*)d_in[2];
    const float* Wv = (const float*)d_in[3];
    const float* Wo = (const float*)d_in[4];
    const float* bo = (const float*)d_in[5];
    float* out = (float*)d_out;

    const size_t elems = (size_t)NROWS * D;     // 6,291,456
    unsigned short* xb   = (unsigned short*)d_ws;
    unsigned short* wt   = xb + elems;          // 4 * 768 * 768
    unsigned short* q    = wt + (size_t)4 * D * D;
    unsigned short* k    = q + elems;
    unsigned short* vt   = k + elems;
    unsigned short* ctxb = vt + elems;          // ends at byte 67,633,152
    int* work_ctr = (int*)((char*)d_ws + CTR_OFF);

    hipMemsetAsync(work_ctr, 0, sizeof(int), stream);

    cvt_x<<<NROWS * D / 1024, 256, 0, stream>>>(x, xb);
    dim3 gw(D / 32, D / 32, 4);
    cvt_w<<<gw, 256, 0, stream>>>(Wq, Wk, Wv, Wo, wt);

    dim3 g1(NROWS / 128, (3 * D) / 128);
    gemm_qkv<<<g1, 256, 0, stream>>>(xb, wt, q, k, vt);

    attn_mfma<<<512, 256, 0, stream>>>(q, k, vt, ctxb, work_ctr);

    dim3 g3(NROWS / 128, D / 128);
    gemm_out<<<g3, 256, 0, stream>>>(ctxb, wt, bo, out);
}

// Round 11
// 258.299 us; speedup vs baseline: 1.0213x; 1.0213x over previous
//
#include <hip/hip_runtime.h>

#define S 4096
#define BATCH 2
#define D 768
#define NH 12
#define DH 64
#define NROWS (BATCH * S)
#define N_ITEMS (32 * NH * BATCH)          // 768 (qt, h, b) work items
#define CTR_OFF 67633152                   // byte offset of queue counter in ws

typedef __attribute__((ext_vector_type(8))) short bf16x8;   // 8 bf16 (4 VGPRs)
typedef __attribute__((ext_vector_type(4))) float f32x4;

__device__ __forceinline__ unsigned short f2bf(float f) {
    unsigned u = __builtin_bit_cast(unsigned, f);
    u += 0x7fff + ((u >> 16) & 1);          // round-to-nearest-even
    return (unsigned short)(u >> 16);
}

__device__ __forceinline__ float fexp2(float x) {
#if __has_builtin(__builtin_amdgcn_exp2f)
    return __builtin_amdgcn_exp2f(x);       // raw v_exp_f32
#else
    return exp2f(x);
#endif
}

// async global->LDS, 16B per lane; lds ptr must be wave-uniform
#define GLDS16(g, l)                                                   \
    __builtin_amdgcn_global_load_lds(                                  \
        (const __attribute__((address_space(1))) void*)(g),            \
        (__attribute__((address_space(3))) void*)(l), 16, 0, 0)

// ---------------------------------------------------------------------------
// x (fp32 [8192][768]) -> bf16. grid 6144 x 256.
// ---------------------------------------------------------------------------
__global__ __launch_bounds__(256) void cvt_x(const float* __restrict__ x,
                                             unsigned short* __restrict__ xb)
{
    int i = (blockIdx.x * 256 + threadIdx.x) * 4;
    float4 v = *(const float4*)(x + i);
    ushort4 o = make_ushort4(f2bf(v.x), f2bf(v.y), f2bf(v.z), f2bf(v.w));
    *(ushort4*)(xb + i) = o;
}

// ---------------------------------------------------------------------------
// W[k][n] fp32 -> wt[z][n][k] bf16 (transposed), z in {Wq,Wk,Wv,Wo}.
// grid (24, 24, 4) x 256; 32x32 LDS tile.
// ---------------------------------------------------------------------------
__global__ __launch_bounds__(256) void cvt_w(
    const float* __restrict__ Wq, const float* __restrict__ Wk,
    const float* __restrict__ Wv, const float* __restrict__ Wo,
    unsigned short* __restrict__ wt)
{
    __shared__ float tile[32][33];
    const int z = blockIdx.z;
    const float* W = (z == 0) ? Wq : (z == 1) ? Wk : (z == 2) ? Wv : Wo;
    const int k0 = blockIdx.x * 32, n0 = blockIdx.y * 32;
    const int t = threadIdx.x;
    const int r = t >> 3, c4 = (t & 7) * 4;

    float4 v = *(const float4*)(W + (size_t)(k0 + r) * D + n0 + c4);
    tile[r][c4 + 0] = v.x; tile[r][c4 + 1] = v.y;
    tile[r][c4 + 2] = v.z; tile[r][c4 + 3] = v.w;
    __syncthreads();
    ushort4 o = make_ushort4(f2bf(tile[c4 + 0][r]), f2bf(tile[c4 + 1][r]),
                             f2bf(tile[c4 + 2][r]), f2bf(tile[c4 + 3][r]));
    *(ushort4*)(wt + ((size_t)z * D + n0 + r) * D + k0 + c4) = o;
}

// ---------------------------------------------------------------------------
// QKV GEMM, bf16 MFMA. A = xb [8192][768], B = wt[z][n][k] (z = n0/768).
// 128x128 tile, BK=64, global_load_lds staging with XOR-8 swizzle.
// Q is pre-scaled by 0.125*log2(e) so attention softmax can use exp2.
// grid (64, 18). (Direct scatter epilogues: measured faster than LDS
// bounces in r10 — L2 absorbs the strided writes.)
// ---------------------------------------------------------------------------
__global__ __launch_bounds__(256) void gemm_qkv(
    const unsigned short* __restrict__ xb,
    const unsigned short* __restrict__ wt,
    unsigned short* __restrict__ qb, unsigned short* __restrict__ kb,
    unsigned short* __restrict__ vtb)
{
    __shared__ unsigned short As[128 * 64];
    __shared__ unsigned short Bs[128 * 64];

    const int t = threadIdx.x;
    const int lane = t & 63, w = t >> 6;
    const int l16 = lane & 15, quad = lane >> 4;
    const int wm = w & 1, wn = w >> 1;
    const int m0 = blockIdx.x * 128;
    const int n0g = blockIdx.y * 128;
    const int z = n0g / 768;
    const int c0 = n0g - z * 768;
    const unsigned short* Wz = wt + (size_t)z * D * D;

    f32x4 acc[4][4] = {};

    for (int k0 = 0; k0 < D; k0 += 64) {
#pragma unroll
        for (int i = 0; i < 4; ++i) {
            int g = i * 256 + w * 64 + lane;
            int row = g >> 3, cl = g & 7, cg = cl ^ (row & 7);
            GLDS16(xb + (size_t)(m0 + row) * D + k0 + cg * 8,
                   As + (size_t)(i * 256 + w * 64) * 8);
            GLDS16(Wz + (size_t)(c0 + row) * D + k0 + cg * 8,
                   Bs + (size_t)(i * 256 + w * 64) * 8);
        }
        __syncthreads();
#pragma unroll
        for (int kk = 0; kk < 2; ++kk) {
            bf16x8 af[4], bf_[4];
#pragma unroll
            for (int mt = 0; mt < 4; ++mt) {
                int r = wm * 64 + mt * 16 + l16;
                int c = kk * 4 + quad;
                af[mt] = *(const bf16x8*)&As[(r * 8 + (c ^ (r & 7))) * 8];
            }
#pragma unroll
            for (int nt = 0; nt < 4; ++nt) {
                int r = wn * 64 + nt * 16 + l16;
                int c = kk * 4 + quad;
                bf_[nt] = *(const bf16x8*)&Bs[(r * 8 + (c ^ (r & 7))) * 8];
            }
#pragma unroll
            for (int mt = 0; mt < 4; ++mt)
#pragma unroll
                for (int nt = 0; nt < 4; ++nt)
                    acc[mt][nt] = __builtin_amdgcn_mfma_f32_16x16x32_bf16(
                        af[mt], bf_[nt], acc[mt][nt], 0, 0, 0);
        }
        __syncthreads();
    }

    if (z < 2) {
        unsigned short* outp = (z == 0) ? qb : kb;
        const float scale = (z == 0) ? 0.18033688011112042f : 1.0f; // .125*log2e
#pragma unroll
        for (int mt = 0; mt < 4; ++mt) {
#pragma unroll
            for (int reg = 0; reg < 4; ++reg) {
                int m = wm * 64 + mt * 16 + quad * 4 + reg;
                int ng = m0 + m;
                int b = ng >> 12, s = ng & 4095;
#pragma unroll
                for (int nt = 0; nt < 4; ++nt) {
                    int n = c0 + wn * 64 + nt * 16 + l16;
                    int h = n >> 6, dh = n & 63;
                    outp[(((size_t)b * NH + h) * S + s) * DH + dh] =
                        f2bf(acc[mt][nt][reg] * scale);
                }
            }
        }
    } else {
#pragma unroll
        for (int mt = 0; mt < 4; ++mt) {
#pragma unroll
            for (int nt = 0; nt < 4; ++nt) {
                int m = wm * 64 + mt * 16 + quad * 4;
                int ng = m0 + m;
                int b = ng >> 12, s = ng & 4095;
                int n = c0 + wn * 64 + nt * 16 + l16;
                int h = n >> 6, dh = n & 63;
                ushort4 p = make_ushort4(
                    f2bf(acc[mt][nt][0]), f2bf(acc[mt][nt][1]),
                    f2bf(acc[mt][nt][2]), f2bf(acc[mt][nt][3]));
                *(ushort4*)(vtb + (((size_t)b * NH + h) * DH + dh) * S + s) = p;
            }
        }
    }
}

// ---------------------------------------------------------------------------
// Flash attention v7: identical to r8 kernel (measured best) except grid
// raised to 640 blocks: LDS 49.6 KB and VGPR 92 allow 3 blocks/CU, so ~2.5
// blocks/CU average raises inter-block latency hiding; the dynamic work
// queue self-corrects the uneven blocks-per-CU (CUs with 3 resident blocks
// pull more items). 128 leftover items are all shallow (qt<=5) -> fine tail.
// Block 256 = 4 waves x 32 q-rows. LDS: K/V dbuf 32K + Ps 16K = 48K.
// ---------------------------------------------------------------------------
__global__ __launch_bounds__(256) void attn_mfma(
    const unsigned short* __restrict__ qg,
    const unsigned short* __restrict__ kg,
    const unsigned short* __restrict__ vtg,
    unsigned short* __restrict__ ctxb,
    int* __restrict__ work_ctr)
{
    __shared__ unsigned short Ks[2][64 * 64];  // [key][dh], XOR-8 swizzle
    __shared__ unsigned short Vs[2][64 * 64];  // [dh][key], XOR-8 swizzle
    __shared__ unsigned short Ps[4][32][64];   // per-wave P: [qrow32][key]
    __shared__ int s_item;

    const float INF = __builtin_inff();
    const int t = threadIdx.x;
    const int w = t >> 6, lane = t & 63;
    const int l16 = lane & 15, quad = lane >> 4;
    const int a7 = l16 & 7;
    const int sg = w * 64 + lane;

    for (;;) {
        if (t == 0) s_item = atomicAdd(work_ctr, 1);
        __syncthreads();                 // broadcast item; prior LDS use done
        const int p = s_item;
        if (p >= N_ITEMS) return;        // uniform exit

        const int qt = 31 - (p / (NH * BATCH));   // longest first
        const int hb = p % (NH * BATCH);
        const int h = hb % NH, b = hb / NH;
        const size_t hbase = ((size_t)b * NH + h) * (size_t)S * DH;
        const unsigned short* kp = kg + hbase;
        const unsigned short* vp = vtg + hbase;

        // Q^T B-fragments for 2 strips (reused across all tiles)
        bf16x8 bq[2][2];
#pragma unroll
        for (int qs = 0; qs < 2; ++qs) {
            int qrow = qt * 128 + w * 32 + qs * 16 + l16;
#pragma unroll
            for (int kk = 0; kk < 2; ++kk)
                bq[qs][kk] = *(const bf16x8*)(qg + hbase + (size_t)qrow * DH +
                                              kk * 32 + quad * 8);
        }

        f32x4 acc_o[2][4] = {};          // O^T: row = dh-local, col = qrow = l16
        float lsum[2] = {0.f, 0.f};      // lane-local partial row sums

        const int jmax = 2 * qt + 1, jd = 2 * qt;

        // preload tile 0 into buffer 0
#pragma unroll
        for (int i = 0; i < 2; ++i) {
            int g = i * 256 + sg;
            int row = g >> 3, cl = g & 7, cg = cl ^ (row & 7);
            GLDS16(kp + (size_t)row * DH + cg * 8,
                   &Ks[0][(size_t)(i * 256 + w * 64) * 8]);
            GLDS16(vp + (size_t)row * S + cg * 8,
                   &Vs[0][(size_t)(i * 256 + w * 64) * 8]);
        }

        for (int j = 0; j <= jmax; ++j) {
            const int cur = j & 1;
            __syncthreads();             // drains tile-j loads; buf cur^1 free
            if (j < jmax) {              // prefetch j+1, overlaps compute
#pragma unroll
                for (int i = 0; i < 2; ++i) {
                    int g = i * 256 + sg;
                    int row = g >> 3, cl = g & 7, cg = cl ^ (row & 7);
                    GLDS16(kp + (size_t)((j + 1) * 64 + row) * DH + cg * 8,
                           &Ks[cur ^ 1][(size_t)(i * 256 + w * 64) * 8]);
                    GLDS16(vp + (size_t)row * S + (j + 1) * 64 + cg * 8,
                           &Vs[cur ^ 1][(size_t)(i * 256 + w * 64) * 8]);
                }
            }

            const unsigned short* Kc = Ks[cur];
            const unsigned short* Vc = Vs[cur];

            // --- S^T = K Q^T ---
            f32x4 acc_s[2][4] = {};
#pragma unroll
            for (int kk = 0; kk < 2; ++kk)
#pragma unroll
                for (int ms = 0; ms < 4; ++ms) {
                    int r = ms * 16 + l16, c = kk * 4 + quad;
                    bf16x8 ak = *(const bf16x8*)&Kc[(r * 8 + (c ^ a7)) * 8];
#pragma unroll
                    for (int qs = 0; qs < 2; ++qs)
                        acc_s[qs][ms] = __builtin_amdgcn_mfma_f32_16x16x32_bf16(
                            ak, bq[qs][kk], acc_s[qs][ms], 0, 0, 0);
                }

            // --- causal mask: only the 2 diagonal tiles (uniform branch) ---
            if (j >= jd) {
#pragma unroll
                for (int qs = 0; qs < 2; ++qs) {
                    int qrow_g = qt * 128 + w * 32 + qs * 16 + l16;
#pragma unroll
                    for (int ms = 0; ms < 4; ++ms)
#pragma unroll
                        for (int reg = 0; reg < 4; ++reg)
                            if ((j * 64 + ms * 16 + quad * 4 + reg) > qrow_g)
                                acc_s[qs][ms][reg] = -INF;   // exp2 -> 0
                }
            }

            // --- fixed-max softmax: P = exp2(S), lane-local partial sums ---
#pragma unroll
            for (int qs = 0; qs < 2; ++qs) {
#pragma unroll
                for (int ms = 0; ms < 4; ++ms) {
                    float e0 = fexp2(acc_s[qs][ms][0]);
                    float e1 = fexp2(acc_s[qs][ms][1]);
                    float e2 = fexp2(acc_s[qs][ms][2]);
                    float e3 = fexp2(acc_s[qs][ms][3]);
                    lsum[qs] += (e0 + e1) + (e2 + e3);
                    unsigned u01 = __builtin_amdgcn_perm(
                        __builtin_bit_cast(unsigned, e1),
                        __builtin_bit_cast(unsigned, e0), 0x07060302u);
                    unsigned u23 = __builtin_amdgcn_perm(
                        __builtin_bit_cast(unsigned, e3),
                        __builtin_bit_cast(unsigned, e2), 0x07060302u);
                    int c8 = ms * 2 + (quad >> 1);
                    *(uint2*)&Ps[w][qs * 16 + l16]
                               [(c8 ^ a7) * 8 + (quad & 1) * 4] =
                        make_uint2(u01, u23);
                }
            }

            // --- O^T += V^T P^T (no rescale needed) ---
#pragma unroll
            for (int kk = 0; kk < 2; ++kk) {
                bf16x8 bp[2];
#pragma unroll
                for (int qs = 0; qs < 2; ++qs)
                    bp[qs] = *(const bf16x8*)&Ps[w][qs * 16 + l16]
                                                [((kk * 4 + quad) ^ a7) * 8];
#pragma unroll
                for (int d = 0; d < 4; ++d) {
                    int r = d * 16 + l16, c = kk * 4 + quad;
                    bf16x8 av = *(const bf16x8*)&Vc[(r * 8 + (c ^ a7)) * 8];
#pragma unroll
                    for (int qs = 0; qs < 2; ++qs)
                        acc_o[qs][d] = __builtin_amdgcn_mfma_f32_16x16x32_bf16(
                            av, bp[qs], acc_o[qs][d], 0, 0, 0);
                }
            }
        }

        // --- epilogue: reduce lsum across quads once; write O^T direct ---
#pragma unroll
        for (int qs = 0; qs < 2; ++qs) {
            float tot = lsum[qs];
            tot += __shfl_xor(tot, 16);
            tot += __shfl_xor(tot, 32);
            float inv = 1.f / tot;
            lsum[qs] = 0.f;              // reset for next queue item
            int qrow = qt * 128 + w * 32 + qs * 16 + l16;
            size_t base = ((size_t)(b * S + qrow)) * D + h * 64;
#pragma unroll
            for (int d = 0; d < 4; ++d) {
                ushort4 o;
                o.x = f2bf(acc_o[qs][d][0] * inv);
                o.y = f2bf(acc_o[qs][d][1] * inv);
                o.z = f2bf(acc_o[qs][d][2] * inv);
                o.w = f2bf(acc_o[qs][d][3] * inv);
                *(ushort4*)(ctxb + base + d * 16 + quad * 4) = o;
            }
        }
    }
}

// ---------------------------------------------------------------------------
// Output projection, bf16 MFMA. A = ctxb [8192][768], B = wt[3] (Wo^T),
// +bias, fp32 out. grid (64, 6).
// ---------------------------------------------------------------------------
__global__ __launch_bounds__(256) void gemm_out(
    const unsigned short* __restrict__ ctxb,
    const unsigned short* __restrict__ wt,
    const float* __restrict__ bo,
    float* __restrict__ out)
{
    __shared__ unsigned short As[128 * 64];
    __shared__ unsigned short Bs[128 * 64];

    const int t = threadIdx.x;
    const int lane = t & 63, w = t >> 6;
    const int l16 = lane & 15, quad = lane >> 4;
    const int wm = w & 1, wn = w >> 1;
    const int m0 = blockIdx.x * 128;
    const int n0 = blockIdx.y * 128;
    const unsigned short* Wz = wt + (size_t)3 * D * D;

    f32x4 acc[4][4] = {};

    for (int k0 = 0; k0 < D; k0 += 64) {
#pragma unroll
        for (int i = 0; i < 4; ++i) {
            int g = i * 256 + w * 64 + lane;
            int row = g >> 3, cl = g & 7, cg = cl ^ (row & 7);
            GLDS16(ctxb + (size_t)(m0 + row) * D + k0 + cg * 8,
                   As + (size_t)(i * 256 + w * 64) * 8);
            GLDS16(Wz + (size_t)(n0 + row) * D + k0 + cg * 8,
                   Bs + (size_t)(i * 256 + w * 64) * 8);
        }
        __syncthreads();
#pragma unroll
        for (int kk = 0; kk < 2; ++kk) {
            bf16x8 af[4], bf_[4];
#pragma unroll
            for (int mt = 0; mt < 4; ++mt) {
                int r = wm * 64 + mt * 16 + l16;
                int c = kk * 4 + quad;
                af[mt] = *(const bf16x8*)&As[(r * 8 + (c ^ (r & 7))) * 8];
            }
#pragma unroll
            for (int nt = 0; nt < 4; ++nt) {
                int r = wn * 64 + nt * 16 + l16;
                int c = kk * 4 + quad;
                bf_[nt] = *(const bf16x8*)&Bs[(r * 8 + (c ^ (r & 7))) * 8];
            }
#pragma unroll
            for (int mt = 0; mt < 4; ++mt)
#pragma unroll
                for (int nt = 0; nt < 4; ++nt)
                    acc[mt][nt] = __builtin_amdgcn_mfma_f32_16x16x32_bf16(
                        af[mt], bf_[nt], acc[mt][nt], 0, 0, 0);
        }
        __syncthreads();
    }

    float bv[4];
#pragma unroll
    for (int nt = 0; nt < 4; ++nt)
        bv[nt] = bo[n0 + wn * 64 + nt * 16 + l16];
#pragma unroll
    for (int mt = 0; mt < 4; ++mt)
#pragma unroll
        for (int reg = 0; reg < 4; ++reg) {
            int m = m0 + wm * 64 + mt * 16 + quad * 4 + reg;
#pragma unroll
            for (int nt = 0; nt < 4; ++nt)
                out[(size_t)m * D + n0 + wn * 64 + nt * 16 + l16] =
                    acc[mt][nt][reg] + bv[nt];
        }
}

extern "C" void kernel_launch(void* const* d_in, const int* in_sizes, int n_in,
                              void* d_out, int out_size, void* d_ws, size_t ws_size,
                              hipStream_t stream)
{
    const float* x  = (const float*)d_in[0];
    const float* Wq = (const float*)d_in[1];
    const float* Wk = (const float*)d_in[2];
    const float* Wv = (const float*)d_in[3];
    const float* Wo = (const float*)d_in[4];
    const float* bo = (const float*)d_in[5];
    float* out = (float*)d_out;

    const size_t elems = (size_t)NROWS * D;     // 6,291,456
    unsigned short* xb   = (unsigned short*)d_ws;
    unsigned short* wt   = xb + elems;          // 4 * 768 * 768
    unsigned short* q    = wt + (size_t)4 * D * D;
    unsigned short* k    = q + elems;
    unsigned short* vt   = k + elems;
    unsigned short* ctxb = vt + elems;          // ends at byte 67,633,152
    int* work_ctr = (int*)((char*)d_ws + CTR_OFF);

    hipMemsetAsync(work_ctr, 0, sizeof(int), stream);

    cvt_x<<<NROWS * D / 1024, 256, 0, stream>>>(x, xb);
    dim3 gw(D / 32, D / 32, 4);
    cvt_w<<<gw, 256, 0, stream>>>(Wq, Wk, Wv, Wo, wt);

    dim3 g1(NROWS / 128, (3 * D) / 128);
    gemm_qkv<<<g1, 256, 0, stream>>>(xb, wt, q, k, vt);

    attn_mfma<<<640, 256, 0, stream>>>(q, k, vt, ctxb, work_ctr);

    dim3 g3(NROWS / 128, D / 128);
    gemm_out<<<g3, 256, 0, stream>>>(ctxb, wt, bo, out);
}